// Round 1
// baseline (192.386 us; speedup 1.0000x reference)
//
#include <hip/hip_runtime.h>
#include <cstddef>

// ---------------------------------------------------------------------------
// MultiHead attention, B=4 T=1024 D=1024 N=16 DH=64, SCALE=32, causal + bias.
// bf16 MFMA pipeline; fp32 softmax; fp32 output.
// ---------------------------------------------------------------------------

typedef __attribute__((ext_vector_type(8))) short bf16x8;
typedef __attribute__((ext_vector_type(4))) float f32x4;

#define MFMA16(a, b, c) __builtin_amdgcn_mfma_f32_16x16x32_bf16(a, b, c, 0, 0, 0)

__device__ __forceinline__ short f2bf(float f) {
  union { float f; unsigned int i; } v; v.f = f;
  unsigned int r = v.i + 0x7FFFu + ((v.i >> 16) & 1u);  // RNE
  return (short)(r >> 16);
}

__device__ __forceinline__ void gload_lds16(const void* g, void* l) {
  __builtin_amdgcn_global_load_lds(
      (const __attribute__((address_space(1))) void*)g,
      (__attribute__((address_space(3))) void*)l, 16, 0, 0);
}

// ---------------------------------------------------------------------------
// f32 -> bf16 conversion (vectorized)
// ---------------------------------------------------------------------------
__global__ __launch_bounds__(256) void cvt_kernel(const float* __restrict__ src,
                                                  short* __restrict__ dst, int n) {
  int stride = gridDim.x * blockDim.x * 4;
  for (int i = (blockIdx.x * blockDim.x + threadIdx.x) * 4; i < n; i += stride) {
    float4 v = *(const float4*)(src + i);
    short4 o;
    o.x = f2bf(v.x); o.y = f2bf(v.y); o.z = f2bf(v.z); o.w = f2bf(v.w);
    *(short4*)(dst + i) = o;
  }
}

// ---------------------------------------------------------------------------
// Shared GEMM core: C[128x128] = A[128xK] * W[128xK]^T, K=1024, BK=64.
// LDS tiles [128 rows][64 bf16] = 128B rows, XOR-swizzled (16B granule ^ row&7)
// so ds_read_b128 fragment reads are ~conflict-free. Staged via global_load_lds
// width 16 (linear dest + inverse-swizzled global source).
// 4 waves in 2x2; each wave computes 64x64 via 4x4 frags of 16x16x32 MFMA.
// ---------------------------------------------------------------------------
__device__ __forceinline__ void gemm_core(const short* __restrict__ A,
                                          const short* __restrict__ W,
                                          int m0, int n0,
                                          short* As, short* Bs,
                                          f32x4 (&acc)[4][4]) {
  const int tid = threadIdx.x;
  const int wid = tid >> 6, lane = tid & 63;
  const int wr = wid >> 1, wc = wid & 1;
  const int fr = lane & 15, fq = lane >> 4;

  for (int kt = 0; kt < 16; ++kt) {
#pragma unroll
    for (int c = 0; c < 4; ++c) {
      int pbase = c * 4096 + wid * 1024;          // physical byte base (uniform)
      int pb = pbase + lane * 16;                 // per-lane physical byte
      int lb = pb ^ (((pb >> 7) & 7) << 4);       // logical byte (involution)
      int grow = lb >> 7, gcol = (lb & 127) >> 1;
      gload_lds16(A + (size_t)(m0 + grow) * 1024 + kt * 64 + gcol, (char*)As + pbase);
      gload_lds16(W + (size_t)(n0 + grow) * 1024 + kt * 64 + gcol, (char*)Bs + pbase);
    }
    __syncthreads();
#pragma unroll
    for (int kk = 0; kk < 2; ++kk) {
      bf16x8 af[4], bg[4];
#pragma unroll
      for (int m = 0; m < 4; ++m) {
        int r = wr * 64 + m * 16 + fr;
        int cb = (fq * 8 + kk * 32) * 2;
        af[m] = *(const bf16x8*)((const char*)As + (((r << 7) + cb) ^ ((r & 7) << 4)));
      }
#pragma unroll
      for (int n = 0; n < 4; ++n) {
        int r = wc * 64 + n * 16 + fr;
        int cb = (fq * 8 + kk * 32) * 2;
        bg[n] = *(const bf16x8*)((const char*)Bs + (((r << 7) + cb) ^ ((r & 7) << 4)));
      }
#pragma unroll
      for (int m = 0; m < 4; ++m)
#pragma unroll
        for (int n = 0; n < 4; ++n)
          acc[m][n] = MFMA16(af[m], bg[n], acc[m][n]);
    }
    __syncthreads();
  }
}

// ---------------------------------------------------------------------------
// Fused Q/K/V projection: z = 0/1/2 selects input & epilogue layout.
// Q,K -> [B,N,T,DH] bf16 ; V -> [B,N,DH,T] bf16 (transposed for PV B-frags).
// ---------------------------------------------------------------------------
__global__ __launch_bounds__(256) void proj_qkv(
    const short* __restrict__ qA, const short* __restrict__ kA, const short* __restrict__ vA,
    const short* __restrict__ Wqb, const short* __restrict__ Wkb, const short* __restrict__ Wvb,
    const float* __restrict__ bq, const float* __restrict__ bk, const float* __restrict__ bv,
    short* __restrict__ Qh, short* __restrict__ Kh, short* __restrict__ Vth) {
  __shared__ short As[128 * 64];
  __shared__ short Bs[128 * 64];
  const int m0 = blockIdx.x * 128;
  const int n0 = blockIdx.y * 128;
  const int z = blockIdx.z;

  const short *A, *W;
  const float* bias;
  if (z == 0)      { A = qA; W = Wqb; bias = bq; }
  else if (z == 1) { A = kA; W = Wkb; bias = bk; }
  else             { A = vA; W = Wvb; bias = bv; }

  f32x4 acc[4][4] = {};
  gemm_core(A, W, m0, n0, As, Bs, acc);

  const int tid = threadIdx.x;
  const int wid = tid >> 6, lane = tid & 63;
  const int wr = wid >> 1, wc = wid & 1;
  const int fr = lane & 15, fq = lane >> 4;

#pragma unroll
  for (int m = 0; m < 4; ++m) {
#pragma unroll
    for (int n = 0; n < 4; ++n) {
      int col = n0 + wc * 64 + n * 16 + fr;
      float bval = bias[col];
      int row0 = m0 + wr * 64 + m * 16 + fq * 4;
      int hh = col >> 6, dh = col & 63;
      if (z < 2) {
        short* dst = (z == 0) ? Qh : Kh;
#pragma unroll
        for (int j = 0; j < 4; ++j) {
          int row = row0 + j;
          int bb = row >> 10, t = row & 1023;
          dst[(((size_t)(bb * 16 + hh)) * 1024 + t) * 64 + dh] = f2bf(acc[m][n][j] + bval);
        }
      } else {
        int bb = row0 >> 10, t0 = row0 & 1023;  // 4 consecutive t, same bb
        short4 sv;
        sv.x = f2bf(acc[m][n][0] + bval);
        sv.y = f2bf(acc[m][n][1] + bval);
        sv.z = f2bf(acc[m][n][2] + bval);
        sv.w = f2bf(acc[m][n][3] + bval);
        *(short4*)&Vth[(((size_t)(bb * 16 + hh)) * 64 + dh) * 1024 + t0] = sv;
      }
    }
  }
}

// ---------------------------------------------------------------------------
// Output projection: d_out[4096][1024] f32 = attn(bf16) @ Wo^T + bo
// ---------------------------------------------------------------------------
__global__ __launch_bounds__(256) void gemm_out(const short* __restrict__ A,
                                                const short* __restrict__ W,
                                                const float* __restrict__ bias,
                                                float* __restrict__ C) {
  __shared__ short As[128 * 64];
  __shared__ short Bs[128 * 64];
  const int m0 = blockIdx.x * 128;
  const int n0 = blockIdx.y * 128;

  f32x4 acc[4][4] = {};
  gemm_core(A, W, m0, n0, As, Bs, acc);

  const int tid = threadIdx.x;
  const int wid = tid >> 6, lane = tid & 63;
  const int wr = wid >> 1, wc = wid & 1;
  const int fr = lane & 15, fq = lane >> 4;

#pragma unroll
  for (int m = 0; m < 4; ++m) {
#pragma unroll
    for (int n = 0; n < 4; ++n) {
      int col = n0 + wc * 64 + n * 16 + fr;
      float bval = bias[col];
      int row0 = m0 + wr * 64 + m * 16 + fq * 4;
#pragma unroll
      for (int j = 0; j < 4; ++j)
        C[(size_t)(row0 + j) * 1024 + col] = acc[m][n][j] + bval;
    }
  }
}

// ---------------------------------------------------------------------------
// Flash attention per head: grid (16 q-tiles, 64 heads), 256 thr (4 waves).
// Wave w handles 16 q rows. KV tiles of 64; causal early exit (kt <= qi).
// S = (Q K^T + bias)/32  - masks;  online softmax fp32;  O += P V.
// ---------------------------------------------------------------------------
__global__ __launch_bounds__(256) void attn_kernel(
    const short* __restrict__ Qh, const short* __restrict__ Kh,
    const short* __restrict__ Vth, const float* __restrict__ Wb,
    const float* __restrict__ mask, short* __restrict__ Aout) {
  __shared__ short Ks[64 * 64];
  __shared__ short Vs[64 * 64];
  __shared__ short Ps[4][16 * 80];  // per-wave P tile, padded rows (160B)
  __shared__ float Ms[64];

  const int tid = threadIdx.x;
  const int wid = tid >> 6, lane = tid & 63;
  const int fr = lane & 15, fq = lane >> 4;
  const int h = blockIdx.y, b = h >> 4;
  const int qi = blockIdx.x, q0 = qi * 64;
  const int qrow0 = q0 + wid * 16;

  // Q fragments (held in regs for whole kernel)
  const short* qbase = Qh + ((size_t)h * 1024 + qrow0 + fr) * 64 + fq * 8;
  bf16x8 qf0 = *(const bf16x8*)qbase;
  bf16x8 qf1 = *(const bf16x8*)(qbase + 32);

  f32x4 o_acc[4] = {};
  float m_run[4], l_run[4];
#pragma unroll
  for (int j = 0; j < 4; ++j) { m_run[j] = -3.0e38f; l_run[j] = 0.f; }
  const float* wbase = Wb + (size_t)h * 1024 * 1024;

  for (int kt = 0; kt <= qi; ++kt) {
    const int k0 = kt * 64;
    // stage K tile [64 t][64 dh] and Vt tile [64 dh][64 t] (swizzled)
#pragma unroll
    for (int c = 0; c < 2; ++c) {
      int pbase = c * 4096 + wid * 1024;
      int pb = pbase + lane * 16;
      int lb = pb ^ (((pb >> 7) & 7) << 4);
      int grow = lb >> 7, gcol = (lb & 127) >> 1;
      gload_lds16(Kh + ((size_t)h * 1024 + k0 + grow) * 64 + gcol, (char*)Ks + pbase);
      gload_lds16(Vth + ((size_t)h * 64 + grow) * 1024 + k0 + gcol, (char*)Vs + pbase);
    }
    if (tid < 64) Ms[tid] = mask[b * 1024 + k0 + tid];
    // bias tile -> regs in MFMA C-layout
    float bias_v[4][4];
#pragma unroll
    for (int nt = 0; nt < 4; ++nt)
#pragma unroll
      for (int j = 0; j < 4; ++j)
        bias_v[nt][j] = wbase[(size_t)(qrow0 + fq * 4 + j) * 1024 + (k0 + nt * 16 + fr)];
    __syncthreads();

    // S = Q K^T
    f32x4 s_acc[4] = {};
#pragma unroll
    for (int kk = 0; kk < 2; ++kk)
#pragma unroll
      for (int nt = 0; nt < 4; ++nt) {
        int r = nt * 16 + fr;
        int cb = (fq * 8 + kk * 32) * 2;
        bf16x8 kf = *(const bf16x8*)((const char*)Ks + (((r << 7) + cb) ^ ((r & 7) << 4)));
        s_acc[nt] = MFMA16(kk == 0 ? qf0 : qf1, kf, s_acc[nt]);
      }

    // scale + bias + masks + online softmax (fp32)
    float p[4][4];
#pragma unroll
    for (int j = 0; j < 4; ++j) {
      const int rq = qrow0 + fq * 4 + j;
      float mx = -3.0e38f;
#pragma unroll
      for (int nt = 0; nt < 4; ++nt) {
        int ck = k0 + nt * 16 + fr;
        float s = (s_acc[nt][j] + bias_v[nt][j]) * 0.03125f
                  - (1.0f - Ms[nt * 16 + fr]) * 3.125e8f;
        if (ck > rq) s = -3.0e38f;  // causal
        p[nt][j] = s;
        mx = fmaxf(mx, s);
      }
#pragma unroll
      for (int d = 1; d < 16; d <<= 1) mx = fmaxf(mx, __shfl_xor(mx, d, 16));
      float mnew = fmaxf(m_run[j], mx);
      float corr = __expf(m_run[j] - mnew);
      m_run[j] = mnew;
      float rsum = 0.f;
#pragma unroll
      for (int nt = 0; nt < 4; ++nt) {
        float e = __expf(p[nt][j] - mnew);
        p[nt][j] = e;
        rsum += e;
      }
#pragma unroll
      for (int d = 1; d < 16; d <<= 1) rsum += __shfl_xor(rsum, d, 16);
      l_run[j] = l_run[j] * corr + rsum;
#pragma unroll
      for (int nt = 0; nt < 4; ++nt) o_acc[nt][j] *= corr;
    }

    // P (C-layout) -> per-wave LDS -> A-layout frags
#pragma unroll
    for (int nt = 0; nt < 4; ++nt)
#pragma unroll
      for (int j = 0; j < 4; ++j)
        Ps[wid][(fq * 4 + j) * 80 + nt * 16 + fr] = f2bf(p[nt][j]);
    asm volatile("s_waitcnt lgkmcnt(0)" ::: "memory");
    bf16x8 pf0 = *(const bf16x8*)&Ps[wid][fr * 80 + fq * 8];
    bf16x8 pf1 = *(const bf16x8*)&Ps[wid][fr * 80 + fq * 8 + 32];

    // O += P V   (Vs[dh][t] rows are V^T -> B-operand frags contiguous)
#pragma unroll
    for (int kk = 0; kk < 2; ++kk)
#pragma unroll
      for (int nt = 0; nt < 4; ++nt) {
        int r = nt * 16 + fr;
        int cb = (fq * 8 + kk * 32) * 2;
        bf16x8 vf = *(const bf16x8*)((const char*)Vs + (((r << 7) + cb) ^ ((r & 7) << 4)));
        o_acc[nt] = MFMA16(kk == 0 ? pf0 : pf1, vf, o_acc[nt]);
      }
    __syncthreads();
  }

  // normalize + write merged-head bf16 [4096][1024]
#pragma unroll
  for (int nt = 0; nt < 4; ++nt)
#pragma unroll
    for (int j = 0; j < 4; ++j) {
      int row = b * 1024 + q0 + wid * 16 + fq * 4 + j;
      int col = (h & 15) * 64 + nt * 16 + fr;
      Aout[(size_t)row * 1024 + col] = f2bf(o_acc[nt][j] / l_run[j]);
    }
}

// ---------------------------------------------------------------------------
extern "C" void kernel_launch(void* const* d_in, const int* in_sizes, int n_in,
                              void* d_out, int out_size, void* d_ws, size_t ws_size,
                              hipStream_t stream) {
  const float* query = (const float*)d_in[0];
  const float* key   = (const float*)d_in[1];
  const float* value = (const float*)d_in[2];
  const float* mask  = (const float*)d_in[3];
  const float* wts   = (const float*)d_in[4];
  const float* Wq    = (const float*)d_in[5];
  const float* bq    = (const float*)d_in[6];
  const float* Wk    = (const float*)d_in[7];
  const float* bk    = (const float*)d_in[8];
  const float* Wv    = (const float*)d_in[9];
  const float* bv    = (const float*)d_in[10];
  const float* Wo    = (const float*)d_in[11];
  const float* bo    = (const float*)d_in[12];

  char* ws = (char*)d_ws;
  const size_t MB = 1u << 20;
  short* qbf = (short*)(ws + 0);        // 8 MB  (reused as attn out)
  short* kbf = (short*)(ws + 8 * MB);   // 8 MB
  short* vbf = (short*)(ws + 16 * MB);  // 8 MB
  short* Wqb = (short*)(ws + 24 * MB);  // 2 MB
  short* Wkb = (short*)(ws + 26 * MB);
  short* Wvb = (short*)(ws + 28 * MB);
  short* Wob = (short*)(ws + 30 * MB);
  short* Qh  = (short*)(ws + 32 * MB);  // 8 MB [B,N,T,DH]
  short* Kh  = (short*)(ws + 40 * MB);  // 8 MB [B,N,T,DH]
  short* Vth = (short*)(ws + 48 * MB);  // 8 MB [B,N,DH,T]
  short* attnb = qbf;                   // alias: qbf dead after proj_qkv

  auto cvt = [&](const float* s, short* d, int n) {
    int nb = (n / 4 + 255) / 256;
    if (nb > 2048) nb = 2048;
    cvt_kernel<<<dim3(nb), dim3(256), 0, stream>>>(s, d, n);
  };
  cvt(query, qbf, 4096 * 1024);
  cvt(key,   kbf, 4096 * 1024);
  cvt(value, vbf, 4096 * 1024);
  cvt(Wq, Wqb, 1024 * 1024);
  cvt(Wk, Wkb, 1024 * 1024);
  cvt(Wv, Wvb, 1024 * 1024);
  cvt(Wo, Wob, 1024 * 1024);

  proj_qkv<<<dim3(32, 8, 3), dim3(256), 0, stream>>>(qbf, kbf, vbf, Wqb, Wkb, Wvb,
                                                     bq, bk, bv, Qh, Kh, Vth);
  attn_kernel<<<dim3(16, 64), dim3(256), 0, stream>>>(Qh, Kh, Vth, wts, mask, attnb);
  gemm_out<<<dim3(32, 8), dim3(256), 0, stream>>>(attnb, Wob, bo, (float*)d_out);
}

// Round 2
// 190.182 us; speedup vs baseline: 1.0116x; 1.0116x over previous
//
#include <hip/hip_runtime.h>
#include <cstddef>

// ---------------------------------------------------------------------------
// MultiHead attention, B=4 T=1024 D=1024 N=16 DH=64, SCALE=32, causal + bias.
// bf16 MFMA pipeline; fp32 softmax; fp32 output.
// Round 2: fused cvt (1 launch), attn double-buffered KV pipeline + heavy-first.
// ---------------------------------------------------------------------------

typedef __attribute__((ext_vector_type(8))) short bf16x8;
typedef __attribute__((ext_vector_type(4))) float f32x4;

#define MFMA16(a, b, c) __builtin_amdgcn_mfma_f32_16x16x32_bf16(a, b, c, 0, 0, 0)

__device__ __forceinline__ short f2bf(float f) {
  union { float f; unsigned int i; } v; v.f = f;
  unsigned int r = v.i + 0x7FFFu + ((v.i >> 16) & 1u);  // RNE
  return (short)(r >> 16);
}

__device__ __forceinline__ void gload_lds16(const void* g, void* l) {
  __builtin_amdgcn_global_load_lds(
      (const __attribute__((address_space(1))) void*)g,
      (__attribute__((address_space(3))) void*)l, 16, 0, 0);
}

// ---------------------------------------------------------------------------
// Fused f32 -> bf16 conversion for all 7 tensors (one launch).
// Layout: chunks of 1M elems: [0..11]=q,k,v (4M each), [12..15]=Wq,Wk,Wv,Wo.
// ---------------------------------------------------------------------------
__global__ __launch_bounds__(256) void cvt_all(
    const float* __restrict__ q, const float* __restrict__ k, const float* __restrict__ v,
    const float* __restrict__ wq, const float* __restrict__ wk,
    const float* __restrict__ wv, const float* __restrict__ wo,
    short* __restrict__ qb, short* __restrict__ kb, short* __restrict__ vb,
    short* __restrict__ wqb, short* __restrict__ wkb,
    short* __restrict__ wvb, short* __restrict__ wob) {
  const int total = 16 * 1048576 / 4;  // vec4 count
  int stride = gridDim.x * blockDim.x;
  for (int i = blockIdx.x * blockDim.x + threadIdx.x; i < total; i += stride) {
    int e = i * 4;
    int chunk = e >> 20;
    const float* s;
    short* d;
    int off;
    if (chunk < 12) {
      if (chunk < 4)      { s = q; d = qb; }
      else if (chunk < 8) { s = k; d = kb; }
      else                { s = v; d = vb; }
      off = e & (4 * 1048576 - 1);
    } else {
      int w = chunk - 12;
      if (w == 0)      { s = wq; d = wqb; }
      else if (w == 1) { s = wk; d = wkb; }
      else if (w == 2) { s = wv; d = wvb; }
      else             { s = wo; d = wob; }
      off = e & (1048576 - 1);
    }
    float4 x = *(const float4*)(s + off);
    short4 o;
    o.x = f2bf(x.x); o.y = f2bf(x.y); o.z = f2bf(x.z); o.w = f2bf(x.w);
    *(short4*)(d + off) = o;
  }
}

// ---------------------------------------------------------------------------
// Shared GEMM core: C[128x128] = A[128xK] * W[128xK]^T, K=1024, BK=64.
// LDS tiles [128 rows][64 bf16] = 128B rows, XOR-swizzled (16B granule ^ row&7).
// Staged via global_load_lds width 16 (linear dest + inverse-swizzled source).
// 4 waves in 2x2; each wave computes 64x64 via 4x4 frags of 16x16x32 MFMA.
// ---------------------------------------------------------------------------
__device__ __forceinline__ void gemm_core(const short* __restrict__ A,
                                          const short* __restrict__ W,
                                          int m0, int n0,
                                          short* As, short* Bs,
                                          f32x4 (&acc)[4][4]) {
  const int tid = threadIdx.x;
  const int wid = tid >> 6, lane = tid & 63;
  const int wr = wid >> 1, wc = wid & 1;
  const int fr = lane & 15, fq = lane >> 4;

  for (int kt = 0; kt < 16; ++kt) {
#pragma unroll
    for (int c = 0; c < 4; ++c) {
      int pbase = c * 4096 + wid * 1024;          // physical byte base (uniform)
      int pb = pbase + lane * 16;                 // per-lane physical byte
      int lb = pb ^ (((pb >> 7) & 7) << 4);       // logical byte (involution)
      int grow = lb >> 7, gcol = (lb & 127) >> 1;
      gload_lds16(A + (size_t)(m0 + grow) * 1024 + kt * 64 + gcol, (char*)As + pbase);
      gload_lds16(W + (size_t)(n0 + grow) * 1024 + kt * 64 + gcol, (char*)Bs + pbase);
    }
    __syncthreads();
#pragma unroll
    for (int kk = 0; kk < 2; ++kk) {
      bf16x8 af[4], bg[4];
#pragma unroll
      for (int m = 0; m < 4; ++m) {
        int r = wr * 64 + m * 16 + fr;
        int cb = (fq * 8 + kk * 32) * 2;
        af[m] = *(const bf16x8*)((const char*)As + (((r << 7) + cb) ^ ((r & 7) << 4)));
      }
#pragma unroll
      for (int n = 0; n < 4; ++n) {
        int r = wc * 64 + n * 16 + fr;
        int cb = (fq * 8 + kk * 32) * 2;
        bg[n] = *(const bf16x8*)((const char*)Bs + (((r << 7) + cb) ^ ((r & 7) << 4)));
      }
#pragma unroll
      for (int m = 0; m < 4; ++m)
#pragma unroll
        for (int n = 0; n < 4; ++n)
          acc[m][n] = MFMA16(af[m], bg[n], acc[m][n]);
    }
    __syncthreads();
  }
}

// ---------------------------------------------------------------------------
// Fused Q/K/V projection: z = 0/1/2 selects input & epilogue layout.
// Q,K -> [B,N,T,DH] bf16 ; V -> [B,N,DH,T] bf16 (transposed for PV B-frags).
// ---------------------------------------------------------------------------
__global__ __launch_bounds__(256) void proj_qkv(
    const short* __restrict__ qA, const short* __restrict__ kA, const short* __restrict__ vA,
    const short* __restrict__ Wqb, const short* __restrict__ Wkb, const short* __restrict__ Wvb,
    const float* __restrict__ bq, const float* __restrict__ bk, const float* __restrict__ bv,
    short* __restrict__ Qh, short* __restrict__ Kh, short* __restrict__ Vth) {
  __shared__ short As[128 * 64];
  __shared__ short Bs[128 * 64];
  const int m0 = blockIdx.x * 128;
  const int n0 = blockIdx.y * 128;
  const int z = blockIdx.z;

  const short *A, *W;
  const float* bias;
  if (z == 0)      { A = qA; W = Wqb; bias = bq; }
  else if (z == 1) { A = kA; W = Wkb; bias = bk; }
  else             { A = vA; W = Wvb; bias = bv; }

  f32x4 acc[4][4] = {};
  gemm_core(A, W, m0, n0, As, Bs, acc);

  const int tid = threadIdx.x;
  const int wid = tid >> 6, lane = tid & 63;
  const int wr = wid >> 1, wc = wid & 1;
  const int fr = lane & 15, fq = lane >> 4;

#pragma unroll
  for (int m = 0; m < 4; ++m) {
#pragma unroll
    for (int n = 0; n < 4; ++n) {
      int col = n0 + wc * 64 + n * 16 + fr;
      float bval = bias[col];
      int row0 = m0 + wr * 64 + m * 16 + fq * 4;
      int hh = col >> 6, dh = col & 63;
      if (z < 2) {
        short* dst = (z == 0) ? Qh : Kh;
#pragma unroll
        for (int j = 0; j < 4; ++j) {
          int row = row0 + j;
          int bb = row >> 10, t = row & 1023;
          dst[(((size_t)(bb * 16 + hh)) * 1024 + t) * 64 + dh] = f2bf(acc[m][n][j] + bval);
        }
      } else {
        int bb = row0 >> 10, t0 = row0 & 1023;  // 4 consecutive t, same bb
        short4 sv;
        sv.x = f2bf(acc[m][n][0] + bval);
        sv.y = f2bf(acc[m][n][1] + bval);
        sv.z = f2bf(acc[m][n][2] + bval);
        sv.w = f2bf(acc[m][n][3] + bval);
        *(short4*)&Vth[(((size_t)(bb * 16 + hh)) * 64 + dh) * 1024 + t0] = sv;
      }
    }
  }
}

// ---------------------------------------------------------------------------
// Output projection: d_out[4096][1024] f32 = attn(bf16) @ Wo^T + bo
// ---------------------------------------------------------------------------
__global__ __launch_bounds__(256) void gemm_out(const short* __restrict__ A,
                                                const short* __restrict__ W,
                                                const float* __restrict__ bias,
                                                float* __restrict__ C) {
  __shared__ short As[128 * 64];
  __shared__ short Bs[128 * 64];
  const int m0 = blockIdx.x * 128;
  const int n0 = blockIdx.y * 128;

  f32x4 acc[4][4] = {};
  gemm_core(A, W, m0, n0, As, Bs, acc);

  const int tid = threadIdx.x;
  const int wid = tid >> 6, lane = tid & 63;
  const int wr = wid >> 1, wc = wid & 1;
  const int fr = lane & 15, fq = lane >> 4;

#pragma unroll
  for (int m = 0; m < 4; ++m) {
#pragma unroll
    for (int n = 0; n < 4; ++n) {
      int col = n0 + wc * 64 + n * 16 + fr;
      float bval = bias[col];
      int row0 = m0 + wr * 64 + m * 16 + fq * 4;
#pragma unroll
      for (int j = 0; j < 4; ++j)
        C[(size_t)(row0 + j) * 1024 + col] = acc[m][n][j] + bval;
    }
  }
}

// ---------------------------------------------------------------------------
// Flash attention per head: grid (16 q-tiles, 64 heads), 256 thr (4 waves).
// Wave w handles 16 q rows. KV tiles of 64, double-buffered LDS:
//   prologue stage(t=0); loop { stage(t+1) ; compute(t) ; barrier }.
// Heavy-first q-tile ordering to shrink the causal-imbalance tail.
// S = (Q K^T + bias)/32 - masks;  online softmax fp32;  O += P V.
// ---------------------------------------------------------------------------
__global__ __launch_bounds__(256) void attn_kernel(
    const short* __restrict__ Qh, const short* __restrict__ Kh,
    const short* __restrict__ Vth, const float* __restrict__ Wb,
    const float* __restrict__ mask, short* __restrict__ Aout) {
  __shared__ short Ks[2][64 * 64];
  __shared__ short Vs[2][64 * 64];
  __shared__ short Ps[4][16 * 80];  // per-wave P tile, padded rows (160B)

  const int tid = threadIdx.x;
  const int wid = tid >> 6, lane = tid & 63;
  const int fr = lane & 15, fq = lane >> 4;
  const int h = blockIdx.y, b = h >> 4;
  const int qi = (int)gridDim.x - 1 - (int)blockIdx.x;  // heavy tiles first
  const int q0 = qi * 64;
  const int qrow0 = q0 + wid * 16;

  // Q fragments (held in regs for whole kernel)
  const short* qbase = Qh + ((size_t)h * 1024 + qrow0 + fr) * 64 + fq * 8;
  bf16x8 qf0 = *(const bf16x8*)qbase;
  bf16x8 qf1 = *(const bf16x8*)(qbase + 32);

  auto stage = [&](int buf, int k0) {
#pragma unroll
    for (int c = 0; c < 2; ++c) {
      int pbase = c * 4096 + wid * 1024;
      int pb = pbase + lane * 16;
      int lb = pb ^ (((pb >> 7) & 7) << 4);
      int grow = lb >> 7, gcol = (lb & 127) >> 1;
      gload_lds16(Kh + ((size_t)h * 1024 + k0 + grow) * 64 + gcol, (char*)Ks[buf] + pbase);
      gload_lds16(Vth + ((size_t)h * 64 + grow) * 1024 + k0 + gcol, (char*)Vs[buf] + pbase);
    }
  };

  f32x4 o_acc[4] = {};
  float m_run[4], l_run[4];
#pragma unroll
  for (int j = 0; j < 4; ++j) { m_run[j] = -3.0e38f; l_run[j] = 0.f; }
  const float* wbase = Wb + (size_t)h * 1024 * 1024;

  stage(0, 0);
  __syncthreads();
  int cur = 0;

  for (int kt = 0; kt <= qi; ++kt) {
    const int k0 = kt * 64;
    if (kt < qi) stage(cur ^ 1, k0 + 64);  // prefetch next tile (in flight all phase)

    // bias tile -> regs (C-layout); mask -> regs
    float bias_v[4][4];
    float mk[4];
#pragma unroll
    for (int nt = 0; nt < 4; ++nt) {
      mk[nt] = mask[b * 1024 + k0 + nt * 16 + fr];
#pragma unroll
      for (int j = 0; j < 4; ++j)
        bias_v[nt][j] = wbase[(size_t)(qrow0 + fq * 4 + j) * 1024 + (k0 + nt * 16 + fr)];
    }

    // S = Q K^T
    f32x4 s_acc[4] = {};
#pragma unroll
    for (int kk = 0; kk < 2; ++kk)
#pragma unroll
      for (int nt = 0; nt < 4; ++nt) {
        int r = nt * 16 + fr;
        int cb = (fq * 8 + kk * 32) * 2;
        bf16x8 kf = *(const bf16x8*)((const char*)Ks[cur] + (((r << 7) + cb) ^ ((r & 7) << 4)));
        s_acc[nt] = MFMA16(kk == 0 ? qf0 : qf1, kf, s_acc[nt]);
      }

    // scale + bias + masks + online softmax (fp32)
    float p[4][4];
#pragma unroll
    for (int j = 0; j < 4; ++j) {
      const int rq = qrow0 + fq * 4 + j;
      float mx = -3.0e38f;
#pragma unroll
      for (int nt = 0; nt < 4; ++nt) {
        int ck = k0 + nt * 16 + fr;
        float s = (s_acc[nt][j] + bias_v[nt][j]) * 0.03125f
                  - (1.0f - mk[nt]) * 3.125e8f;
        if (ck > rq) s = -3.0e38f;  // causal
        p[nt][j] = s;
        mx = fmaxf(mx, s);
      }
#pragma unroll
      for (int d = 1; d < 16; d <<= 1) mx = fmaxf(mx, __shfl_xor(mx, d, 16));
      float mnew = fmaxf(m_run[j], mx);
      float corr = __expf(m_run[j] - mnew);
      m_run[j] = mnew;
      float rsum = 0.f;
#pragma unroll
      for (int nt = 0; nt < 4; ++nt) {
        float e = __expf(p[nt][j] - mnew);
        p[nt][j] = e;
        rsum += e;
      }
#pragma unroll
      for (int d = 1; d < 16; d <<= 1) rsum += __shfl_xor(rsum, d, 16);
      l_run[j] = l_run[j] * corr + rsum;
#pragma unroll
      for (int nt = 0; nt < 4; ++nt) o_acc[nt][j] *= corr;
    }

    // P (C-layout) -> per-wave LDS -> A-layout frags
#pragma unroll
    for (int nt = 0; nt < 4; ++nt)
#pragma unroll
      for (int j = 0; j < 4; ++j)
        Ps[wid][(fq * 4 + j) * 80 + nt * 16 + fr] = f2bf(p[nt][j]);
    asm volatile("s_waitcnt lgkmcnt(0)" ::: "memory");
    bf16x8 pf0 = *(const bf16x8*)&Ps[wid][fr * 80 + fq * 8];
    bf16x8 pf1 = *(const bf16x8*)&Ps[wid][fr * 80 + fq * 8 + 32];

    // O += P V   (Vs[dh][t] rows are V^T -> B-operand frags contiguous)
#pragma unroll
    for (int kk = 0; kk < 2; ++kk)
#pragma unroll
      for (int nt = 0; nt < 4; ++nt) {
        int r = nt * 16 + fr;
        int cb = (fq * 8 + kk * 32) * 2;
        bf16x8 vf = *(const bf16x8*)((const char*)Vs[cur] + (((r << 7) + cb) ^ ((r & 7) << 4)));
        o_acc[nt] = MFMA16(kk == 0 ? pf0 : pf1, vf, o_acc[nt]);
      }
    __syncthreads();  // drains prefetch vmcnt + protects Ks/Vs[cur] reuse
    cur ^= 1;
  }

  // normalize + write merged-head bf16 [4096][1024]
#pragma unroll
  for (int nt = 0; nt < 4; ++nt)
#pragma unroll
    for (int j = 0; j < 4; ++j) {
      int row = b * 1024 + q0 + wid * 16 + fq * 4 + j;
      int col = (h & 15) * 64 + nt * 16 + fr;
      Aout[(size_t)row * 1024 + col] = f2bf(o_acc[nt][j] / l_run[j]);
    }
}

// ---------------------------------------------------------------------------
extern "C" void kernel_launch(void* const* d_in, const int* in_sizes, int n_in,
                              void* d_out, int out_size, void* d_ws, size_t ws_size,
                              hipStream_t stream) {
  const float* query = (const float*)d_in[0];
  const float* key   = (const float*)d_in[1];
  const float* value = (const float*)d_in[2];
  const float* mask  = (const float*)d_in[3];
  const float* wts   = (const float*)d_in[4];
  const float* Wq    = (const float*)d_in[5];
  const float* bq    = (const float*)d_in[6];
  const float* Wk    = (const float*)d_in[7];
  const float* bk    = (const float*)d_in[8];
  const float* Wv    = (const float*)d_in[9];
  const float* bv    = (const float*)d_in[10];
  const float* Wo    = (const float*)d_in[11];
  const float* bo    = (const float*)d_in[12];

  char* ws = (char*)d_ws;
  const size_t MB = 1u << 20;
  short* qbf = (short*)(ws + 0);        // 8 MB  (reused as attn out)
  short* kbf = (short*)(ws + 8 * MB);   // 8 MB
  short* vbf = (short*)(ws + 16 * MB);  // 8 MB
  short* Wqb = (short*)(ws + 24 * MB);  // 2 MB
  short* Wkb = (short*)(ws + 26 * MB);
  short* Wvb = (short*)(ws + 28 * MB);
  short* Wob = (short*)(ws + 30 * MB);
  short* Qh  = (short*)(ws + 32 * MB);  // 8 MB [B,N,T,DH]
  short* Kh  = (short*)(ws + 40 * MB);  // 8 MB [B,N,T,DH]
  short* Vth = (short*)(ws + 48 * MB);  // 8 MB [B,N,DH,T]
  short* attnb = qbf;                   // alias: qbf dead after proj_qkv

  cvt_all<<<dim3(2048), dim3(256), 0, stream>>>(query, key, value, Wq, Wk, Wv, Wo,
                                                qbf, kbf, vbf, Wqb, Wkb, Wvb, Wob);
  proj_qkv<<<dim3(32, 8, 3), dim3(256), 0, stream>>>(qbf, kbf, vbf, Wqb, Wkb, Wvb,
                                                     bq, bk, bv, Qh, Kh, Vth);
  attn_kernel<<<dim3(16, 64), dim3(256), 0, stream>>>(Qh, Kh, Vth, wts, mask, attnb);
  gemm_out<<<dim3(32, 8), dim3(256), 0, stream>>>(attnb, Wob, bo, (float*)d_out);
}

// Round 3
// 183.777 us; speedup vs baseline: 1.0468x; 1.0349x over previous
//
#include <hip/hip_runtime.h>
#include <cstddef>

// ---------------------------------------------------------------------------
// MultiHead attention, B=4 T=1024 D=1024 N=16 DH=64, SCALE=32, causal + bias.
// Round 3: 256x64 GEMM tiles (2x MFMA:stage), LDS-repacked V-transpose write,
// 8-wave gemm_out, register-prefetched bias in attn.
// ---------------------------------------------------------------------------

typedef __attribute__((ext_vector_type(8))) short bf16x8;
typedef __attribute__((ext_vector_type(4))) float f32x4;

#define MFMA16(a, b, c) __builtin_amdgcn_mfma_f32_16x16x32_bf16(a, b, c, 0, 0, 0)

__device__ __forceinline__ short f2bf(float f) {
  union { float f; unsigned int i; } v; v.f = f;
  unsigned int r = v.i + 0x7FFFu + ((v.i >> 16) & 1u);  // RNE
  return (short)(r >> 16);
}

__device__ __forceinline__ void gload_lds16(const void* g, void* l) {
  __builtin_amdgcn_global_load_lds(
      (const __attribute__((address_space(1))) void*)g,
      (__attribute__((address_space(3))) void*)l, 16, 0, 0);
}

// ---------------------------------------------------------------------------
// Fused f32 -> bf16 conversion for all 7 tensors (one launch).
// ---------------------------------------------------------------------------
__global__ __launch_bounds__(256) void cvt_all(
    const float* __restrict__ q, const float* __restrict__ k, const float* __restrict__ v,
    const float* __restrict__ wq, const float* __restrict__ wk,
    const float* __restrict__ wv, const float* __restrict__ wo,
    short* __restrict__ qb, short* __restrict__ kb, short* __restrict__ vb,
    short* __restrict__ wqb, short* __restrict__ wkb,
    short* __restrict__ wvb, short* __restrict__ wob) {
  const int total = 16 * 1048576 / 4;  // vec4 count
  int stride = gridDim.x * blockDim.x;
  for (int i = blockIdx.x * blockDim.x + threadIdx.x; i < total; i += stride) {
    int e = i * 4;
    int chunk = e >> 20;
    const float* s;
    short* d;
    int off;
    if (chunk < 12) {
      if (chunk < 4)      { s = q; d = qb; }
      else if (chunk < 8) { s = k; d = kb; }
      else                { s = v; d = vb; }
      off = e & (4 * 1048576 - 1);
    } else {
      int w = chunk - 12;
      if (w == 0)      { s = wq; d = wqb; }
      else if (w == 1) { s = wk; d = wkb; }
      else if (w == 2) { s = wv; d = wvb; }
      else             { s = wo; d = wob; }
      off = e & (1048576 - 1);
    }
    float4 x = *(const float4*)(s + off);
    short4 o;
    o.x = f2bf(x.x); o.y = f2bf(x.y); o.z = f2bf(x.z); o.w = f2bf(x.w);
    *(short4*)(d + off) = o;
  }
}

// ---------------------------------------------------------------------------
// Fused Q/K/V projection: 256x64 tile, 4 waves stacked (64 rows each), BK=64.
// LDS rows 128B, XOR-swizzled (16B granule ^ row&7). 32 MFMA / 10 loads per
// wave-iter. Q,K -> [B,N,T,DH]; V -> [B,N,DH,T] via LDS repack (coalesced).
// ---------------------------------------------------------------------------
__global__ __launch_bounds__(256) void proj_qkv(
    const short* __restrict__ qA, const short* __restrict__ kA, const short* __restrict__ vA,
    const short* __restrict__ Wqb, const short* __restrict__ Wkb, const short* __restrict__ Wvb,
    const float* __restrict__ bq, const float* __restrict__ bk, const float* __restrict__ bv,
    short* __restrict__ Qh, short* __restrict__ Kh, short* __restrict__ Vth) {
  __shared__ short SMEM[256 * 64 + 64 * 64];  // As(32K) + Bs(8K); reused as Vt
  short* As = SMEM;
  short* Bs = SMEM + 256 * 64;

  const int m0 = blockIdx.x * 256;
  const int n0 = blockIdx.y * 64;
  const int z = blockIdx.z;

  const short *A, *W;
  const float* bias;
  if (z == 0)      { A = qA; W = Wqb; bias = bq; }
  else if (z == 1) { A = kA; W = Wkb; bias = bk; }
  else             { A = vA; W = Wvb; bias = bv; }

  const int tid = threadIdx.x;
  const int wid = tid >> 6, lane = tid & 63;
  const int fr = lane & 15, fq = lane >> 4;

  f32x4 acc[4][4] = {};

  for (int kt = 0; kt < 16; ++kt) {
#pragma unroll
    for (int c = 0; c < 8; ++c) {
      int pbase = c * 4096 + wid * 1024;
      int pb = pbase + lane * 16;
      int lb = pb ^ (((pb >> 7) & 7) << 4);
      int grow = lb >> 7, gcol = (lb & 127) >> 1;
      gload_lds16(A + (size_t)(m0 + grow) * 1024 + kt * 64 + gcol, (char*)As + pbase);
    }
#pragma unroll
    for (int c = 0; c < 2; ++c) {
      int pbase = c * 4096 + wid * 1024;
      int pb = pbase + lane * 16;
      int lb = pb ^ (((pb >> 7) & 7) << 4);
      int grow = lb >> 7, gcol = (lb & 127) >> 1;
      gload_lds16(W + (size_t)(n0 + grow) * 1024 + kt * 64 + gcol, (char*)Bs + pbase);
    }
    __syncthreads();
#pragma unroll
    for (int kk = 0; kk < 2; ++kk) {
      bf16x8 af[4], bg[4];
      int cb = (fq * 8 + kk * 32) * 2;
#pragma unroll
      for (int m = 0; m < 4; ++m) {
        int r = wid * 64 + m * 16 + fr;
        af[m] = *(const bf16x8*)((const char*)As + (((r << 7) + cb) ^ ((r & 7) << 4)));
      }
#pragma unroll
      for (int n = 0; n < 4; ++n) {
        int r = n * 16 + fr;
        bg[n] = *(const bf16x8*)((const char*)Bs + (((r << 7) + cb) ^ ((r & 7) << 4)));
      }
#pragma unroll
      for (int m = 0; m < 4; ++m)
#pragma unroll
        for (int n = 0; n < 4; ++n)
          acc[m][n] = MFMA16(af[m], bg[n], acc[m][n]);
    }
    __syncthreads();
  }

  if (z < 2) {
    short* dst = (z == 0) ? Qh : Kh;
#pragma unroll
    for (int m = 0; m < 4; ++m)
#pragma unroll
      for (int n = 0; n < 4; ++n) {
        int col = n0 + n * 16 + fr;
        float bval = bias[col];
        int row0 = m0 + wid * 64 + m * 16 + fq * 4;
        int hh = col >> 6, dh = col & 63;
#pragma unroll
        for (int j = 0; j < 4; ++j) {
          int row = row0 + j;
          int bb = row >> 10, t = row & 1023;
          dst[(((size_t)(bb * 16 + hh)) * 1024 + t) * 64 + dh] = f2bf(acc[m][n][j] + bval);
        }
      }
  } else {
    // Repack V block (rows m0..m0+255 x cols n0..n0+63) transposed into LDS,
    // then write coalesced 512B rows of Vth[head][dh][t].
    short* Vt = SMEM;  // [64][264] shorts (33.8 KB <= 40 KB)
#pragma unroll
    for (int m = 0; m < 4; ++m)
#pragma unroll
      for (int n = 0; n < 4; ++n) {
        int coll = n * 16 + fr;
        float bval = bias[n0 + coll];
        int rowl0 = wid * 64 + m * 16 + fq * 4;
#pragma unroll
        for (int j = 0; j < 4; ++j)
          Vt[coll * 264 + rowl0 + j] = f2bf(acc[m][n][j] + bval);
      }
    __syncthreads();
    const int bb = m0 >> 10, t0 = m0 & 1023;
#pragma unroll
    for (int it = 0; it < 8; ++it) {
      int qq = tid + it * 256;          // 0..2047 : (64 rows) x (32 x 16B)
      int rowl = qq >> 5, seg = qq & 31;
      bf16x8 vv = *(const bf16x8*)&Vt[rowl * 264 + seg * 8];
      int cg = n0 + rowl, hh = cg >> 6, dh = cg & 63;
      *(bf16x8*)&Vth[(((size_t)(bb * 16 + hh)) * 64 + dh) * 1024 + t0 + seg * 8] = vv;
    }
  }
}

// ---------------------------------------------------------------------------
// Output projection: 512 thr / 8 waves, 256x64 tile. d_out f32 = A@Wo^T + bo.
// ---------------------------------------------------------------------------
__global__ __launch_bounds__(512) void gemm_out(const short* __restrict__ A,
                                                const short* __restrict__ W,
                                                const float* __restrict__ bias,
                                                float* __restrict__ C) {
  __shared__ short As[256 * 64];
  __shared__ short Bs[64 * 64];
  const int m0 = blockIdx.x * 256;
  const int n0 = blockIdx.y * 64;

  const int tid = threadIdx.x;
  const int wid = tid >> 6, lane = tid & 63;
  const int fr = lane & 15, fq = lane >> 4;

  f32x4 acc[2][4] = {};

  for (int kt = 0; kt < 16; ++kt) {
#pragma unroll
    for (int c = 0; c < 4; ++c) {
      int pbase = c * 8192 + wid * 1024;
      int pb = pbase + lane * 16;
      int lb = pb ^ (((pb >> 7) & 7) << 4);
      int grow = lb >> 7, gcol = (lb & 127) >> 1;
      gload_lds16(A + (size_t)(m0 + grow) * 1024 + kt * 64 + gcol, (char*)As + pbase);
    }
    {
      int pbase = wid * 1024;
      int pb = pbase + lane * 16;
      int lb = pb ^ (((pb >> 7) & 7) << 4);
      int grow = lb >> 7, gcol = (lb & 127) >> 1;
      gload_lds16(W + (size_t)(n0 + grow) * 1024 + kt * 64 + gcol, (char*)Bs + pbase);
    }
    __syncthreads();
#pragma unroll
    for (int kk = 0; kk < 2; ++kk) {
      bf16x8 af[2], bg[4];
      int cb = (fq * 8 + kk * 32) * 2;
#pragma unroll
      for (int m = 0; m < 2; ++m) {
        int r = wid * 32 + m * 16 + fr;
        af[m] = *(const bf16x8*)((const char*)As + (((r << 7) + cb) ^ ((r & 7) << 4)));
      }
#pragma unroll
      for (int n = 0; n < 4; ++n) {
        int r = n * 16 + fr;
        bg[n] = *(const bf16x8*)((const char*)Bs + (((r << 7) + cb) ^ ((r & 7) << 4)));
      }
#pragma unroll
      for (int m = 0; m < 2; ++m)
#pragma unroll
        for (int n = 0; n < 4; ++n)
          acc[m][n] = MFMA16(af[m], bg[n], acc[m][n]);
    }
    __syncthreads();
  }

#pragma unroll
  for (int m = 0; m < 2; ++m)
#pragma unroll
    for (int n = 0; n < 4; ++n) {
      int col = n0 + n * 16 + fr;
      float bval = bias[col];
      int row0 = m0 + wid * 32 + m * 16 + fq * 4;
#pragma unroll
      for (int j = 0; j < 4; ++j)
        C[(size_t)(row0 + j) * 1024 + col] = acc[m][n][j] + bval;
    }
}

// ---------------------------------------------------------------------------
// Flash attention per head: grid (16 q-tiles, 64 heads), 256 thr (4 waves).
// KV tiles of 64, double-buffered LDS; bias register-prefetched one tile
// ahead (T14: issue at iter top, drained by end-of-iter barrier).
// ---------------------------------------------------------------------------
__global__ __launch_bounds__(256) void attn_kernel(
    const short* __restrict__ Qh, const short* __restrict__ Kh,
    const short* __restrict__ Vth, const float* __restrict__ Wb,
    const float* __restrict__ mask, short* __restrict__ Aout) {
  __shared__ short Ks[2][64 * 64];
  __shared__ short Vs[2][64 * 64];
  __shared__ short Ps[4][16 * 80];  // per-wave P tile, padded rows (160B)

  const int tid = threadIdx.x;
  const int wid = tid >> 6, lane = tid & 63;
  const int fr = lane & 15, fq = lane >> 4;
  const int h = blockIdx.y, b = h >> 4;
  const int qi = (int)gridDim.x - 1 - (int)blockIdx.x;  // heavy tiles first
  const int q0 = qi * 64;
  const int qrow0 = q0 + wid * 16;

  const short* qbase = Qh + ((size_t)h * 1024 + qrow0 + fr) * 64 + fq * 8;
  bf16x8 qf0 = *(const bf16x8*)qbase;
  bf16x8 qf1 = *(const bf16x8*)(qbase + 32);

  auto stage = [&](int buf, int k0) {
#pragma unroll
    for (int c = 0; c < 2; ++c) {
      int pbase = c * 4096 + wid * 1024;
      int pb = pbase + lane * 16;
      int lb = pb ^ (((pb >> 7) & 7) << 4);
      int grow = lb >> 7, gcol = (lb & 127) >> 1;
      gload_lds16(Kh + ((size_t)h * 1024 + k0 + grow) * 64 + gcol, (char*)Ks[buf] + pbase);
      gload_lds16(Vth + ((size_t)h * 64 + grow) * 1024 + k0 + gcol, (char*)Vs[buf] + pbase);
    }
  };

  const float* wbase = Wb + (size_t)h * 1024 * 1024;
  auto load_bias = [&](float (&bv)[4][4], int k0) {
#pragma unroll
    for (int nt = 0; nt < 4; ++nt)
#pragma unroll
      for (int j = 0; j < 4; ++j)
        bv[nt][j] = wbase[(size_t)(qrow0 + fq * 4 + j) * 1024 + (k0 + nt * 16 + fr)];
  };

  f32x4 o_acc[4] = {};
  float m_run[4], l_run[4];
#pragma unroll
  for (int j = 0; j < 4; ++j) { m_run[j] = -3.0e38f; l_run[j] = 0.f; }

  float bias_cur[4][4], bias_nxt[4][4];
  stage(0, 0);
  load_bias(bias_cur, 0);
  __syncthreads();
  int cur = 0;

  for (int kt = 0; kt <= qi; ++kt) {
    const int k0 = kt * 64;
    if (kt < qi) {               // prefetch next tile: K/V -> LDS, bias -> regs
      stage(cur ^ 1, k0 + 64);
      load_bias(bias_nxt, k0 + 64);
    }
    float mk[4];
#pragma unroll
    for (int nt = 0; nt < 4; ++nt)
      mk[nt] = mask[b * 1024 + k0 + nt * 16 + fr];

    // S = Q K^T
    f32x4 s_acc[4] = {};
#pragma unroll
    for (int kk = 0; kk < 2; ++kk)
#pragma unroll
      for (int nt = 0; nt < 4; ++nt) {
        int r = nt * 16 + fr;
        int cb = (fq * 8 + kk * 32) * 2;
        bf16x8 kf = *(const bf16x8*)((const char*)Ks[cur] + (((r << 7) + cb) ^ ((r & 7) << 4)));
        s_acc[nt] = MFMA16(kk == 0 ? qf0 : qf1, kf, s_acc[nt]);
      }

    // scale + bias + masks + online softmax (fp32)
    float p[4][4];
#pragma unroll
    for (int j = 0; j < 4; ++j) {
      const int rq = qrow0 + fq * 4 + j;
      float mx = -3.0e38f;
#pragma unroll
      for (int nt = 0; nt < 4; ++nt) {
        int ck = k0 + nt * 16 + fr;
        float s = (s_acc[nt][j] + bias_cur[nt][j]) * 0.03125f
                  - (1.0f - mk[nt]) * 3.125e8f;
        if (ck > rq) s = -3.0e38f;  // causal
        p[nt][j] = s;
        mx = fmaxf(mx, s);
      }
#pragma unroll
      for (int d = 1; d < 16; d <<= 1) mx = fmaxf(mx, __shfl_xor(mx, d, 16));
      float mnew = fmaxf(m_run[j], mx);
      float corr = __expf(m_run[j] - mnew);
      m_run[j] = mnew;
      float rsum = 0.f;
#pragma unroll
      for (int nt = 0; nt < 4; ++nt) {
        float e = __expf(p[nt][j] - mnew);
        p[nt][j] = e;
        rsum += e;
      }
#pragma unroll
      for (int d = 1; d < 16; d <<= 1) rsum += __shfl_xor(rsum, d, 16);
      l_run[j] = l_run[j] * corr + rsum;
#pragma unroll
      for (int nt = 0; nt < 4; ++nt) o_acc[nt][j] *= corr;
    }

    // P (C-layout) -> per-wave LDS -> A-layout frags
#pragma unroll
    for (int nt = 0; nt < 4; ++nt)
#pragma unroll
      for (int j = 0; j < 4; ++j)
        Ps[wid][(fq * 4 + j) * 80 + nt * 16 + fr] = f2bf(p[nt][j]);
    asm volatile("s_waitcnt lgkmcnt(0)" ::: "memory");
    bf16x8 pf0 = *(const bf16x8*)&Ps[wid][fr * 80 + fq * 8];
    bf16x8 pf1 = *(const bf16x8*)&Ps[wid][fr * 80 + fq * 8 + 32];

    // O += P V
#pragma unroll
    for (int kk = 0; kk < 2; ++kk)
#pragma unroll
      for (int nt = 0; nt < 4; ++nt) {
        int r = nt * 16 + fr;
        int cb = (fq * 8 + kk * 32) * 2;
        bf16x8 vf = *(const bf16x8*)((const char*)Vs[cur] + (((r << 7) + cb) ^ ((r & 7) << 4)));
        o_acc[nt] = MFMA16(kk == 0 ? pf0 : pf1, vf, o_acc[nt]);
      }
    __syncthreads();  // drains prefetch vmcnt (after full compute phase)
    if (kt < qi) {
#pragma unroll
      for (int nt = 0; nt < 4; ++nt)
#pragma unroll
        for (int j = 0; j < 4; ++j) bias_cur[nt][j] = bias_nxt[nt][j];
    }
    cur ^= 1;
  }

  // normalize + write merged-head bf16 [4096][1024]
#pragma unroll
  for (int nt = 0; nt < 4; ++nt)
#pragma unroll
    for (int j = 0; j < 4; ++j) {
      int row = b * 1024 + q0 + wid * 16 + fq * 4 + j;
      int col = (h & 15) * 64 + nt * 16 + fr;
      Aout[(size_t)row * 1024 + col] = f2bf(o_acc[nt][j] / l_run[j]);
    }
}

// ---------------------------------------------------------------------------
extern "C" void kernel_launch(void* const* d_in, const int* in_sizes, int n_in,
                              void* d_out, int out_size, void* d_ws, size_t ws_size,
                              hipStream_t stream) {
  const float* query = (const float*)d_in[0];
  const float* key   = (const float*)d_in[1];
  const float* value = (const float*)d_in[2];
  const float* mask  = (const float*)d_in[3];
  const float* wts   = (const float*)d_in[4];
  const float* Wq    = (const float*)d_in[5];
  const float* bq    = (const float*)d_in[6];
  const float* Wk    = (const float*)d_in[7];
  const float* bk    = (const float*)d_in[8];
  const float* Wv    = (const float*)d_in[9];
  const float* bv    = (const float*)d_in[10];
  const float* Wo    = (const float*)d_in[11];
  const float* bo    = (const float*)d_in[12];

  char* ws = (char*)d_ws;
  const size_t MB = 1u << 20;
  short* qbf = (short*)(ws + 0);        // 8 MB  (reused as attn out)
  short* kbf = (short*)(ws + 8 * MB);   // 8 MB
  short* vbf = (short*)(ws + 16 * MB);  // 8 MB
  short* Wqb = (short*)(ws + 24 * MB);  // 2 MB
  short* Wkb = (short*)(ws + 26 * MB);
  short* Wvb = (short*)(ws + 28 * MB);
  short* Wob = (short*)(ws + 30 * MB);
  short* Qh  = (short*)(ws + 32 * MB);  // 8 MB [B,N,T,DH]
  short* Kh  = (short*)(ws + 40 * MB);  // 8 MB [B,N,T,DH]
  short* Vth = (short*)(ws + 48 * MB);  // 8 MB [B,N,DH,T]
  short* attnb = qbf;                   // alias: qbf dead after proj_qkv

  cvt_all<<<dim3(2048), dim3(256), 0, stream>>>(query, key, value, Wq, Wk, Wv, Wo,
                                                qbf, kbf, vbf, Wqb, Wkb, Wvb, Wob);
  proj_qkv<<<dim3(16, 16, 3), dim3(256), 0, stream>>>(qbf, kbf, vbf, Wqb, Wkb, Wvb,
                                                      bq, bk, bv, Qh, Kh, Vth);
  attn_kernel<<<dim3(16, 64), dim3(256), 0, stream>>>(Qh, Kh, Vth, wts, mask, attnb);
  gemm_out<<<dim3(16, 16), dim3(512), 0, stream>>>(attnb, Wob, bo, (float*)d_out);
}